// Round 5
// baseline (433.987 us; speedup 1.0000x reference)
//
#include <hip/hip_runtime.h>
#include <stdint.h>

// NeighborAttention, MI355X gfx950 — round 5: 3-kernel split for concurrency.
// B=4,N=4096,K=32,C=128,H=4,d=32.
//  A: T = (X·WQ^T)·WK per head, scaled -> ws (bf16). Removes prologue+WK gather
//     from the hot kernel (amortized 4x further at 64 nodes/block).
//  B: E-streamer. grid 1024, 16 nodes/block, 4 waves. Per 128x128 E subtile:
//     scores = E·T^T (MFMA, wave=node) -> in-reg shfl softmax -> publish attn
//     (1 barrier) -> HV = E·WV^T (MFMA, wave=col-tile, WV in block-lifetime
//     regs) -> cat rows straight to ws. LDS 46.8 KB -> 3 blocks/CU.
//  C: out = cat·WO^T (MFMA, r4 P7 verbatim).
// dtype (fp32 vs bf16) detected in-kernel per kernel. Numerics identical to r4.

typedef __attribute__((ext_vector_type(8))) short short8;   // 8 bf16 = 16 B
typedef __attribute__((ext_vector_type(4))) float f32x4;

#define CDIM  128
#define KN    32
#define ESTR  136   // padded LDS row stride (bf16 units) for 128-wide tiles
#define SSTR  36    // attn row stride (fp32), 32 attn + [33]=ainv

__device__ __forceinline__ float bf2f(short s) {
    union { unsigned int u; float f; } v;
    v.u = ((unsigned int)(unsigned short)s) << 16;
    return v.f;
}
__device__ __forceinline__ short f2bf(float f) {
    union { float ff; unsigned int u; } v; v.ff = f;
    unsigned int u = v.u;
    u += 0x7FFFu + ((u >> 16) & 1u);   // round-to-nearest-even
    return (short)(u >> 16);
}

template<bool FP32>
__device__ __forceinline__ short8 load8bf(const void* p, size_t idx) {
    if constexpr (FP32) {
        const float* fp = (const float*)p + idx;
        f32x4 a = *(const f32x4*)fp;
        f32x4 b = *(const f32x4*)(fp + 4);
        short8 r;
        r[0] = f2bf(a[0]); r[1] = f2bf(a[1]); r[2] = f2bf(a[2]); r[3] = f2bf(a[3]);
        r[4] = f2bf(b[0]); r[5] = f2bf(b[1]); r[6] = f2bf(b[2]); r[7] = f2bf(b[3]);
        return r;
    } else {
        return *(const short8*)((const short*)p + idx);
    }
}

template<bool FP32>
__device__ __forceinline__ short loadbf1(const void* p, size_t idx) {
    if constexpr (FP32) return f2bf(((const float*)p)[idx]);
    else return ((const short*)p)[idx];
}

// in-kernel dtype detect: fp32 low half-words decode to wild/NaN bf16s
__device__ __forceinline__ bool detect_fp32(const short* wp) {
    const int lane = threadIdx.x & 63;
    int cnt = 0;
    #pragma unroll
    for (int i = 0; i < 8; ++i) {
        const float v = bf2f(wp[lane + i * 64]);
        if (!(fabsf(v) < 8.0f)) cnt++;
    }
    #pragma unroll
    for (int d = 1; d < 64; d <<= 1) cnt += __shfl_xor(cnt, d);
    return cnt > 16;
}

// ===================== kernel A: T precompute =====================
#define ANPB 64
struct alignas(16) SmemA {
    short sX[ANPB * ESTR];   // 17408 B
    short sQ[ANPB * ESTR];   // 17408 B
};                           // 34816 B

template<bool FP32>
__device__ __forceinline__ void naA_body(SmemA& sm, const void* __restrict__ hX,
    const void* __restrict__ WQ, const void* __restrict__ WK, short* __restrict__ Tg)
{
    const int tid = threadIdx.x, lane = tid & 63, w = tid >> 6;
    const int quad = lane >> 4, l15 = lane & 15;
    const int nbA = blockIdx.x * ANPB;

    // stage X (coalesced)
    #pragma unroll
    for (int it = 0; it < 4; ++it) {
        const int chunk = it * 256 + tid, row = chunk >> 4, cc = chunk & 15;
        *(short8*)&sm.sX[row * ESTR + cc * 8] =
            load8bf<FP32>(hX, (size_t)nbA * CDIM + (size_t)chunk * 8);
    }
    // WQ B-frags
    short8 bq[2][4];
    #pragma unroll
    for (int t2 = 0; t2 < 2; ++t2)
        #pragma unroll
        for (int kk = 0; kk < 4; ++kk)
            bq[t2][kk] = load8bf<FP32>(WQ, (size_t)(w * 32 + t2 * 16 + l15) * CDIM + kk * 32 + quad * 8);
    __syncthreads();

    // q = X @ WQ^T
    #pragma unroll
    for (int mt = 0; mt < 4; ++mt) {
        short8 ax[4];
        #pragma unroll
        for (int kk = 0; kk < 4; ++kk)
            ax[kk] = *(const short8*)&sm.sX[(mt * 16 + l15) * ESTR + kk * 32 + quad * 8];
        f32x4 o0 = {0.f,0.f,0.f,0.f}, o1 = {0.f,0.f,0.f,0.f};
        #pragma unroll
        for (int kk = 0; kk < 4; ++kk) {
            o0 = __builtin_amdgcn_mfma_f32_16x16x32_bf16(ax[kk], bq[0][kk], o0, 0, 0, 0);
            o1 = __builtin_amdgcn_mfma_f32_16x16x32_bf16(ax[kk], bq[1][kk], o1, 0, 0, 0);
        }
        #pragma unroll
        for (int r = 0; r < 4; ++r) {
            const int row = mt * 16 + quad * 4 + r;
            sm.sQ[row * ESTR + w * 32 + l15]      = f2bf(o0[r]);
            sm.sQ[row * ESTR + w * 32 + 16 + l15] = f2bf(o1[r]);
        }
    }
    __syncthreads();

    // WK B-frags (scalar gather, once per block, 64 nodes amortized)
    short8 bk[2][4];
    #pragma unroll
    for (int t2 = 0; t2 < 2; ++t2)
        #pragma unroll
        for (int kk = 0; kk < 4; ++kk) {
            const int j = w * 32 + t2 * 16 + l15;
            short8 b;
            #pragma unroll
            for (int jj = 0; jj < 8; ++jj)
                b[jj] = loadbf1<FP32>(WK, (size_t)(kk * 32 + quad * 8 + jj) * CDIM + j);
            bk[t2][kk] = b;
        }

    // t = (q·WK)*scale via masked-head MFMA; rows = (n,h)
    const float scale = 0.17677669529663687f;   // 1/sqrt(32)
    const short8 zz = {0,0,0,0,0,0,0,0};
    #pragma unroll
    for (int m = 0; m < 16; ++m) {
        const int n_g = (m * 16 + l15) >> 2, h_ = l15 & 3;
        const short8 qv = *(const short8*)&sm.sQ[n_g * ESTR + h_ * 32 + quad * 8];
        f32x4 c0 = {0.f,0.f,0.f,0.f}, c1 = {0.f,0.f,0.f,0.f};
        #pragma unroll
        for (int kk = 0; kk < 4; ++kk) {
            const short8 af = (kk == h_) ? qv : zz;
            c0 = __builtin_amdgcn_mfma_f32_16x16x32_bf16(af, bk[0][kk], c0, 0, 0, 0);
            c1 = __builtin_amdgcn_mfma_f32_16x16x32_bf16(af, bk[1][kk], c1, 0, 0, 0);
        }
        #pragma unroll
        for (int r = 0; r < 4; ++r) {
            const int rg = m * 16 + quad * 4 + r;
            const size_t base = (size_t)(nbA + (rg >> 2)) * 512 + (rg & 3) * 128 + w * 32;
            Tg[base + l15]      = f2bf(c0[r] * scale);
            Tg[base + 16 + l15] = f2bf(c1[r] * scale);
        }
    }
}

__global__ __launch_bounds__(256, 3)
void naA(const void* __restrict__ hX, const void* __restrict__ WQ,
         const void* __restrict__ WK, short* __restrict__ Tg)
{
    __shared__ SmemA sm;
    if (detect_fp32((const short*)WQ)) naA_body<true >(sm, hX, WQ, WK, Tg);
    else                               naA_body<false>(sm, hX, WQ, WK, Tg);
}

// ===================== kernel B: E streamer =====================
#define NPB 16
struct alignas(16) SmemB {
    short sE[128 * ESTR];      // 34816 B  E subtile (bf16)
    short sTb[2][16 * ESTR];   //  8704 B  T double buffer
    float sS[16 * SSTR];       //  2304 B  attn rows (+[33]=ainv)
    int   sMask[NPB * KN];     //  2048 B
};                             // 47872 B -> 3 blocks/CU

template<bool FP32>
__device__ __forceinline__ void issueE(const void* hE, size_t base, int tid,
                                       f32x4 (&eF)[8][2], short8 (&eB)[8]) {
    if constexpr (FP32) {
        #pragma unroll
        for (int it = 0; it < 8; ++it) {
            const float* p = (const float*)hE + base + (size_t)(it * 256 + tid) * 8;
            eF[it][0] = *(const f32x4*)p;
            eF[it][1] = *(const f32x4*)(p + 4);
        }
    } else {
        #pragma unroll
        for (int it = 0; it < 8; ++it)
            eB[it] = *(const short8*)((const short*)hE + base + (size_t)(it * 256 + tid) * 8);
    }
}

template<bool FP32>
__device__ __forceinline__ void writeE(short* sE, int tid,
                                       const f32x4 (&eF)[8][2], const short8 (&eB)[8]) {
    #pragma unroll
    for (int it = 0; it < 8; ++it) {
        const int chunk = it * 256 + tid, row = chunk >> 4, cc = chunk & 15;
        short8 v;
        if constexpr (FP32) {
            #pragma unroll
            for (int t = 0; t < 4; ++t) { v[t] = f2bf(eF[it][0][t]); v[4 + t] = f2bf(eF[it][1][t]); }
        } else v = eB[it];
        *(short8*)&sE[row * ESTR + cc * 8] = v;
    }
}

template<bool FP32>
__device__ __forceinline__ void naB_body(SmemB& sm, const void* __restrict__ hE,
    const int* __restrict__ mask, const void* __restrict__ WV,
    const short* __restrict__ Tg, short* __restrict__ catG)
{
    const int tid = threadIdx.x, lane = tid & 63, w = tid >> 6;
    const int quad = lane >> 4, l15 = lane & 15;
    const int nb = blockIdx.x * NPB;
    const size_t ebase = (size_t)nb * (KN * CDIM);

    f32x4 eF[8][2]; short8 eB[8]; short8 eT;
    issueE<FP32>(hE, ebase, tid, eF, eB);
    eT = *(const short8*)(Tg + (size_t)nb * 512 + tid * 8);
    __builtin_amdgcn_sched_barrier(0);   // pin: do not sink prefetch

    // mask stage (coalesced)
    *(int2*)&sm.sMask[tid * 2] = *(const int2*)&mask[(size_t)nb * KN + tid * 2];

    // WV B-frags, block lifetime (wave w owns channel cols 32w..32w+31)
    short8 bv[2][4];
    #pragma unroll
    for (int ct2 = 0; ct2 < 2; ++ct2)
        #pragma unroll
        for (int kk = 0; kk < 4; ++kk)
            bv[ct2][kk] = load8bf<FP32>(WV, (size_t)((2 * w + ct2) * 16 + l15) * CDIM + kk * 32 + quad * 8);

    // stage subtile 0, issue subtile 1
    writeE<FP32>(sm.sE, tid, eF, eB);
    { const int row = tid >> 4, cc = tid & 15;
      *(short8*)&sm.sTb[0][row * ESTR + cc * 8] = eT; }
    issueE<FP32>(hE, ebase + 128 * 128, tid, eF, eB);
    eT = *(const short8*)(Tg + (size_t)(nb + 4) * 512 + tid * 8);
    __builtin_amdgcn_sched_barrier(0);
    __syncthreads();   // B0: sE=E0, sTb0=T0, sMask ready

    #pragma unroll 1
    for (int s = 0; s < 4; ++s) {
        const short* tb = sm.sTb[s & 1];

        // P4: scores = E·T^T for own node (cols l15=(n,h); all computed, n==w kept)
        short8 bs[4], a0[4], a1[4];
        #pragma unroll
        for (int kk = 0; kk < 4; ++kk) {
            bs[kk] = *(const short8*)&tb[l15 * ESTR + kk * 32 + quad * 8];
            a0[kk] = *(const short8*)&sm.sE[(w * 32 + l15) * ESTR + kk * 32 + quad * 8];
            a1[kk] = *(const short8*)&sm.sE[(w * 32 + 16 + l15) * ESTR + kk * 32 + quad * 8];
        }
        f32x4 s0 = {0.f,0.f,0.f,0.f}, s1 = {0.f,0.f,0.f,0.f};
        #pragma unroll
        for (int kk = 0; kk < 4; ++kk) {
            s0 = __builtin_amdgcn_mfma_f32_16x16x32_bf16(a0[kk], bs[kk], s0, 0, 0, 0);
            s1 = __builtin_amdgcn_mfma_f32_16x16x32_bf16(a1[kk], bs[kk], s1, 0, 0, 0);
        }

        // in-register masked softmax (per column (n,h)=l15, k across quads)
        {
            const int* mp = &sm.sMask[(s * 4 + (l15 >> 2)) * KN];
            float x[8]; int mk[8];
            #pragma unroll
            for (int j = 0; j < 4; ++j) {
                x[j] = s0[j];     mk[j]     = mp[quad * 4 + j];
                x[4 + j] = s1[j]; mk[4 + j] = mp[16 + quad * 4 + j];
            }
            float m = -3.0e38f;
            #pragma unroll
            for (int j = 0; j < 8; ++j) m = fmaxf(m, (mk[j] > 0) ? x[j] : -3.0e38f);
            m = fmaxf(m, __shfl_xor(m, 16));
            m = fmaxf(m, __shfl_xor(m, 32));
            float dsum = 0.f;
            #pragma unroll
            for (int j = 0; j < 8; ++j) {
                const float e = __expf(fminf(x[j] - m, 0.f)) * ((mk[j] > 0) ? 1.f : 0.f);
                x[j] = e; dsum += e;
            }
            dsum += __shfl_xor(dsum, 16);
            dsum += __shfl_xor(dsum, 32);
            const float inv = (dsum > 0.f) ? (1.f / dsum) : 0.f;
            if ((l15 >> 2) == w) {              // owner lanes publish attn
                float* sp = &sm.sS[(w * 4 + (l15 & 3)) * SSTR];
                #pragma unroll
                for (int j = 0; j < 4; ++j) {
                    sp[quad * 4 + j]      = x[j] * inv;
                    sp[16 + quad * 4 + j] = x[4 + j] * inv;
                }
                if (quad == 0)
                    sp[33] = 1.0f / (((dsum > 0.f) ? 1.0f : 0.0f) + 1e-8f);
            }
        }
        __syncthreads();   // BA: attn visible to all waves

        // P6: HV + aggregation; wave w = cols 32w..+31 (head h == w), all 4 nodes
        #pragma unroll
        for (int n_ = 0; n_ < 4; ++n_) {
            short8 c0[4], c1[4];
            #pragma unroll
            for (int kk = 0; kk < 4; ++kk) {
                c0[kk] = *(const short8*)&sm.sE[(n_ * 32 + l15) * ESTR + kk * 32 + quad * 8];
                c1[kk] = *(const short8*)&sm.sE[(n_ * 32 + 16 + l15) * ESTR + kk * 32 + quad * 8];
            }
            const float* ap = &sm.sS[(n_ * 4 + w) * SSTR];
            const float ainv = ap[33];
            #pragma unroll
            for (int ct2 = 0; ct2 < 2; ++ct2) {
                f32x4 av0 = {0.f,0.f,0.f,0.f}, av1 = {0.f,0.f,0.f,0.f};
                #pragma unroll
                for (int kk = 0; kk < 4; ++kk) {
                    av0 = __builtin_amdgcn_mfma_f32_16x16x32_bf16(c0[kk], bv[ct2][kk], av0, 0, 0, 0);
                    av1 = __builtin_amdgcn_mfma_f32_16x16x32_bf16(c1[kk], bv[ct2][kk], av1, 0, 0, 0);
                }
                float sum = 0.f, mx = -3.0e38f;
                #pragma unroll
                for (int r = 0; r < 4; ++r) {
                    const float p0 = ap[quad * 4 + r]      * av0[r];
                    const float p1 = ap[16 + quad * 4 + r] * av1[r];
                    sum += p0 + p1;
                    mx = fmaxf(mx, fmaxf(p0, p1));
                }
                sum += __shfl_xor(sum, 16);
                sum += __shfl_xor(sum, 32);
                mx = fmaxf(mx, __shfl_xor(mx, 16));
                mx = fmaxf(mx, __shfl_xor(mx, 32));
                if (quad == 0) {
                    const int c = (2 * w + ct2) * 16 + l15;
                    const size_t ng = (size_t)(nb + s * 4 + n_) * 384;
                    catG[ng + c]       = f2bf(sum * ainv);  // mean
                    catG[ng + 128 + c] = f2bf(sum);         // sum
                    catG[ng + 256 + c] = f2bf(mx);          // max
                }
            }
        }
        __syncthreads();   // BB: all sE reads done

        if (s < 3) {
            writeE<FP32>(sm.sE, tid, eF, eB);   // sE := E[s+1] (vmcnt here)
            { const int row = tid >> 4, cc = tid & 15;
              *(short8*)&sm.sTb[(s + 1) & 1][row * ESTR + cc * 8] = eT; }
            if (s < 2) {
                issueE<FP32>(hE, ebase + (size_t)(s + 2) * 128 * 128, tid, eF, eB);
                eT = *(const short8*)(Tg + (size_t)(nb + (s + 2) * 4) * 512 + tid * 8);
                __builtin_amdgcn_sched_barrier(0);
            }
            __syncthreads();   // BC: next subtile staged
        }
    }
}

__global__ __launch_bounds__(256, 3)
void naB(const void* __restrict__ hE, const int* __restrict__ mask,
         const void* __restrict__ WV, const short* __restrict__ Tg,
         short* __restrict__ catG)
{
    __shared__ SmemB sm;
    if (detect_fp32((const short*)WV)) naB_body<true >(sm, hE, mask, WV, Tg, catG);
    else                               naB_body<false>(sm, hE, mask, WV, Tg, catG);
}

// ===================== kernel C: out = cat @ WO^T =====================
struct alignas(16) SmemC {
    short sCat[16 * 392];   // 12544 B
};

template<bool FP32>
__device__ __forceinline__ void naC_body(SmemC& sm, const short* __restrict__ catG,
    const void* __restrict__ WO, void* __restrict__ out)
{
    const int tid = threadIdx.x, lane = tid & 63, w = tid >> 6;
    const int quad = lane >> 4, l15 = lane & 15;
    const int nb = blockIdx.x * 16;

    // stage cat (coalesced): 768 chunks of 8 bf16
    #pragma unroll
    for (int it = 0; it < 3; ++it) {
        const int chunk = it * 256 + tid;
        const int row = chunk / 48, cc = chunk % 48;
        *(short8*)&sm.sCat[row * 392 + cc * 8] =
            *(const short8*)&catG[(size_t)nb * 384 + (size_t)chunk * 8];
    }
    __syncthreads();

    f32x4 o0 = {0.f,0.f,0.f,0.f}, o1 = {0.f,0.f,0.f,0.f};
    #pragma unroll
    for (int kk = 0; kk < 12; ++kk) {
        const short8 a  = *(const short8*)&sm.sCat[l15 * 392 + kk * 32 + quad * 8];
        const short8 b0 = load8bf<FP32>(WO, (size_t)(w * 32 + l15) * 384 + kk * 32 + quad * 8);
        const short8 b1 = load8bf<FP32>(WO, (size_t)(w * 32 + 16 + l15) * 384 + kk * 32 + quad * 8);
        o0 = __builtin_amdgcn_mfma_f32_16x16x32_bf16(a, b0, o0, 0, 0, 0);
        o1 = __builtin_amdgcn_mfma_f32_16x16x32_bf16(a, b1, o1, 0, 0, 0);
    }
    #pragma unroll
    for (int r = 0; r < 4; ++r) {
        const int node = quad * 4 + r;
        const size_t base = (size_t)(nb + node) * CDIM + w * 32;
        if constexpr (FP32) {
            ((float*)out)[base + l15]      = o0[r];
            ((float*)out)[base + 16 + l15] = o1[r];
        } else {
            ((short*)out)[base + l15]      = f2bf(o0[r]);
            ((short*)out)[base + 16 + l15] = f2bf(o1[r]);
        }
    }
}

__global__ __launch_bounds__(256, 4)
void naC(const short* __restrict__ catG, const void* __restrict__ WO,
         void* __restrict__ out)
{
    __shared__ SmemC sm;
    if (detect_fp32((const short*)WO)) naC_body<true >(sm, catG, WO, out);
    else                               naC_body<false>(sm, catG, WO, out);
}

extern "C" void kernel_launch(void* const* d_in, const int* in_sizes, int n_in,
                              void* d_out, int out_size, void* d_ws, size_t ws_size,
                              hipStream_t stream) {
    (void)in_sizes; (void)n_in; (void)ws_size; (void)out_size;
    const void* hX   = d_in[0];
    const void* hE   = d_in[1];
    const int*  mask = (const int*)d_in[2];
    const void* WQ   = d_in[3];
    const void* WK   = d_in[4];
    const void* WV   = d_in[5];
    const void* WO   = d_in[6];

    short* Tg   = (short*)d_ws;                             // 16384*512*2 = 16.8 MB
    short* catG = (short*)((char*)d_ws + (32u << 20));      // 16384*384*2 = 12.6 MB

    naA<<<dim3(256),  dim3(256), 0, stream>>>(hX, WQ, WK, Tg);
    naB<<<dim3(1024), dim3(256), 0, stream>>>(hE, mask, WV, Tg, catG);
    naC<<<dim3(1024), dim3(256), 0, stream>>>(catG, WO, d_out);
}